// Round 12
// baseline (401.390 us; speedup 1.0000x reference)
//
#include <hip/hip_runtime.h>
#include <hip/hip_bf16.h>

typedef unsigned short u16;
typedef short v8s __attribute__((ext_vector_type(8)));
typedef float v4f __attribute__((ext_vector_type(4)));

#define BATCH 8192
#define IND 10240
#define NODES 1024
#define ACTIONS 64
#define HIDDEN 128

__device__ __forceinline__ u16 f2b(float x) {
    __hip_bfloat16 h = __float2bfloat16(x);
    return *reinterpret_cast<u16*>(&h);
}

__device__ __forceinline__ float b2f(u16 x) {
    unsigned u = ((unsigned)x) << 16;
    return *reinterpret_cast<float*>(&u);
}

__device__ __forceinline__ void gload16(const void* g, void* l) {
    __builtin_amdgcn_global_load_lds(
        (const __attribute__((address_space(1))) void*)g,
        (__attribute__((address_space(3))) void*)l, 16, 0, 0);
}

#define SBAR() do { __builtin_amdgcn_s_barrier(); \
                    __builtin_amdgcn_sched_barrier(0); } while (0)
#define VMCNT4() asm volatile("s_waitcnt vmcnt(4)" ::: "memory")
#define VMCNT0() asm volatile("s_waitcnt vmcnt(0)" ::: "memory")

// ---------------------------------------------------------------------------
// Histogram + entropy gate + E -> bf16 cast (one pass over E).
// ---------------------------------------------------------------------------
__global__ __launch_bounds__(256) void hist_entropy_cast(
    const float* __restrict__ E, u16* __restrict__ Ebf, float* __restrict__ keep)
{
    __shared__ int hist[4][100];
    const int tid = threadIdx.x;
    const int wave = tid >> 6;
    const int b = blockIdx.x;
    for (int j = tid; j < 400; j += 256) ((int*)hist)[j] = 0;
    __syncthreads();

    const float* row = E + (size_t)b * IND;
    u16* orow = Ebf + (size_t)b * IND;
    for (int i = tid * 4; i < IND; i += 1024) {
        float4 v = *reinterpret_cast<const float4*>(row + i);
        float xs[4] = {v.x, v.y, v.z, v.w};
        u16 ob[4];
#pragma unroll
        for (int j = 0; j < 4; ++j) {
            float x = xs[j];
            ob[j] = f2b(x);
            if (x >= -5.0f && x <= 5.0f) {
                int idx = (int)floorf((x + 5.0f) / 10.0f * 100.0f);
                idx = idx < 0 ? 0 : (idx > 99 ? 99 : idx);
                atomicAdd(&hist[wave][idx], 1);
            }
        }
        u16 packed[4] = {ob[0], ob[1], ob[2], ob[3]};
        *reinterpret_cast<uint2*>(orow + i) = *reinterpret_cast<uint2*>(packed);
    }
    __syncthreads();
    if (tid < 100)
        hist[0][tid] = hist[0][tid] + hist[1][tid] + hist[2][tid] + hist[3][tid];
    __syncthreads();

    if (tid < 64) {
        float c0 = (float)hist[0][tid];
        float c1 = (tid < 36) ? (float)hist[0][tid + 64] : 0.0f;
        float tot = c0 + c1;
#pragma unroll
        for (int s = 32; s >= 1; s >>= 1) tot += __shfl_xor(tot, s);
        float denom = tot + 1e-9f;
        float p0 = c0 / denom, p1 = c1 / denom;
        float e = -(p0 * logf(p0 + 1e-9f)) - (p1 * logf(p1 + 1e-9f));
#pragma unroll
        for (int s = 32; s >= 1; s >>= 1) e += __shfl_xor(e, s);
        if (tid == 0) keep[b] = (e >= 2.5f) ? 1.0f : 0.0f;
    }
}

// ---------------------------------------------------------------------------
// f32 -> bf16 elementwise
// ---------------------------------------------------------------------------
__global__ __launch_bounds__(256) void cvt_bf16(
    const float* __restrict__ in, u16* __restrict__ out, long n4)
{
    long i = (long)blockIdx.x * blockDim.x + threadIdx.x;
    const long stride = (long)gridDim.x * blockDim.x;
    for (; i < n4; i += stride) {
        float4 v = reinterpret_cast<const float4*>(in)[i];
        u16 o[4] = {f2b(v.x), f2b(v.y), f2b(v.z), f2b(v.w)};
        reinterpret_cast<uint2*>(out)[i] = *reinterpret_cast<uint2*>(o);
    }
}

// ---------------------------------------------------------------------------
// transpose + convert: in f32 [R][C] -> out bf16 [C][R]
// ---------------------------------------------------------------------------
__global__ void transpose_cvt(const float* __restrict__ in, u16* __restrict__ out,
                              int R, int C)
{
    __shared__ float t[32][33];
    const int bx = blockIdx.x * 32, by = blockIdx.y * 32;
    const int tx = threadIdx.x, ty = threadIdx.y;  // 32 x 8
#pragma unroll
    for (int j = 0; j < 32; j += 8) {
        int r = by + ty + j, c = bx + tx;
        if (r < R && c < C) t[ty + j][tx] = in[(size_t)r * C + c];
    }
    __syncthreads();
#pragma unroll
    for (int j = 0; j < 32; j += 8) {
        int oc = by + tx;
        int orow = bx + ty + j;
        if (orow < C && oc < R) out[(size_t)orow * R + oc] = f2b(t[tx][ty + j]);
    }
}

// ---------------------------------------------------------------------------
// w2sum[i] = sum_a W2[a][i]
// ---------------------------------------------------------------------------
__global__ void w2sum_k(const float* __restrict__ W2, float* __restrict__ w2s)
{
    int i = threadIdx.x;
    if (i < HIDDEN) {
        float s = 0.f;
        for (int a = 0; a < ACTIONS; ++a) s += W2[a * HIDDEN + i];
        w2s[i] = s;
    }
}

// ---------------------------------------------------------------------------
// semantic loss reduction (2-stage, deterministic)
// ---------------------------------------------------------------------------
__global__ __launch_bounds__(256) void semloss1(
    const float* __restrict__ A, const float* __restrict__ M, float* __restrict__ part)
{
    const int tid = threadIdx.x;
    float s = 0.f;
    for (int i = blockIdx.x * 256 + tid; i < NODES * NODES; i += 256 * gridDim.x)
        s += fabsf(A[i]) * M[i];
    __shared__ float ws[4];
#pragma unroll
    for (int off = 32; off >= 1; off >>= 1) s += __shfl_xor(s, off);
    if ((tid & 63) == 0) ws[tid >> 6] = s;
    __syncthreads();
    if (tid == 0) part[blockIdx.x] = ws[0] + ws[1] + ws[2] + ws[3];
}

__global__ void semloss2(const float* __restrict__ part, float* __restrict__ out, int n)
{
    const int tid = threadIdx.x;
    float s = (tid < n) ? part[tid] : 0.f;
    __shared__ float ws[4];
#pragma unroll
    for (int off = 32; off >= 1; off >>= 1) s += __shfl_xor(s, off);
    if ((tid & 63) == 0) ws[tid >> 6] = s;
    __syncthreads();
    if (tid == 0) out[0] = ws[0] + ws[1] + ws[2] + ws[3];
}

// ---------------------------------------------------------------------------
// combine split-K partials.
// KEEP=1: filt = bf16((p0+p1) * keep[row]);  KEEP=0: out = bf16(p0+p1)
// ---------------------------------------------------------------------------
template<int KEEP>
__global__ __launch_bounds__(256) void combine_k(
    const float* __restrict__ p0, const float* __restrict__ p1,
    const float* __restrict__ keep, u16* __restrict__ outb)
{
    long base = ((long)blockIdx.x * 256 + threadIdx.x) * 4;
    float4 a = *reinterpret_cast<const float4*>(p0 + base);
    float4 b = *reinterpret_cast<const float4*>(p1 + base);
    float k = KEEP ? keep[base >> 10] : 1.0f;
    u16 o[4] = {f2b((a.x + b.x) * k), f2b((a.y + b.y) * k),
                f2b((a.z + b.z) * k), f2b((a.w + b.w) * k)};
    *reinterpret_cast<uint2*>(outb + base) = *reinterpret_cast<uint2*>(o);
}

// ---------------------------------------------------------------------------
// 256x256 tile bf16 GEMM, C = A @ B^T, f32 partials (split-K over blockIdx.z).
// Parametrized on (ld, nt): K per z = nt*64; used for E@S^T (ld=10240,nt=80)
// and filt@Atb^T (ld=1024,nt=8). 8 waves (2M x 4N), wave tile 128x64.
// LDS 128 KiB: A chunk (buf,kh) at (buf*2+kh)*16384, B at 65536+...;
// 16B blocks XOR-swizzled by (row>>1)&3; stage = linear LDS dest +
// inverse-swizzled global source (rule #21).
//
// SINGLE BARRIER PER PHASE (vs R6/R8/R11's two): phase =
//   {ds_read frags; stage chunk; [vmcnt]; setprio(1); MFMA x16; setprio(0);
//    BAR}. The old pre-MFMA barrier forced global lockstep (all waves jam
// LDS, then all MFMA); with one barrier, wave skew (bounded to 1 phase)
// lets reads(p+1) of one wave overlap MFMA(p) of another.
// Forcing chain (unchanged vmcnt placement, re-verified):
//   t.ph2 vmcnt(4): outstanding {A1(t),B1(t),A0(t+1),B0(t+1)} -> forces
//     A1(t),B1(t); BAR end-ph2; read at ph3.  OK
//   t.ph4 vmcnt(4): forces A0(t+1),B0(t+1); BAR end-ph4; read t+1.ph1. OK
// Stage targets buffer P^1 while reads target P; max skew 1 phase -> no
// write/read conflict. Tail tile: no stage, VMCNT0 at ph2.
// ---------------------------------------------------------------------------
__device__ __forceinline__ void stage_chunk(
    const u16* __restrict__ g, int ld, char* lds, int chunk_off, int kt_col,
    int tid, int wave)
{
    const int s_row0 = tid >> 2;
    const int gblk = (tid & 3) ^ ((tid >> 3) & 3);  // inverse swizzle
#pragma unroll
    for (int j = 0; j < 2; ++j) {
        int lrow = j * 128 + s_row0;
        gload16(g + (size_t)lrow * ld + kt_col + (gblk << 3),
                lds + chunk_off + j * 8192 + (wave << 10));
    }
}

__global__ __launch_bounds__(512, 2) void gemm8_ep0(
    const u16* __restrict__ A, const u16* __restrict__ B,
    int ld, int nt, float* __restrict__ outf)
{
    extern __shared__ char lds[];
    const int tid = threadIdx.x;
    const int wave = tid >> 6, lane = tid & 63;
    const int wr = wave >> 2, wcn = wave & 3;   // 2M x 4N
    const int l15 = lane & 15, lhi = lane >> 4;
    const int rsw = (lhi ^ ((l15 >> 1) & 3)) << 4;  // read-side swizzled block byte
    const size_t koff = (size_t)blockIdx.z * ((size_t)nt * 64);
    const u16* Ag = A + (size_t)(blockIdx.x * 256) * ld + koff;
    const u16* Bg = B + (size_t)(blockIdx.y * 256) * ld + koff;

    v4f acc[8][4];
#pragma unroll
    for (int m = 0; m < 8; ++m)
#pragma unroll
        for (int n = 0; n < 4; ++n) acc[m][n] = (v4f){0.f, 0.f, 0.f, 0.f};

    v8s aq[4], bq[4];
    const int arow = wr * 128 * 64;        // byte offset of wave's A row range
    const int brow0 = wcn * 64 * 64;       // byte offset of wave's B row range

#define LDA(P, KS, M) (*reinterpret_cast<const v8s*>( \
    lds + ((P)*2 + (KS)) * 16384 + arow + ((M)*16 + l15) * 64 + rsw))
#define LDB(P, KS, NF) (*reinterpret_cast<const v8s*>( \
    lds + 65536 + ((P)*2 + (KS)) * 16384 + brow0 + ((NF)*16 + l15) * 64 + rsw))
#define QMFMA(MB) do { \
    _Pragma("unroll") \
    for (int m = 0; m < 4; ++m) \
        _Pragma("unroll") \
        for (int n = 0; n < 4; ++n) \
            acc[(MB) + m][n] = __builtin_amdgcn_mfma_f32_16x16x32_bf16( \
                aq[m], bq[n], acc[(MB) + m][n], 0, 0, 0); \
    } while (0)

#define TILE(P, KTN, STG) do { \
    /* ---- ph1: mh0, ks0 ---- */ \
    _Pragma("unroll") \
    for (int m = 0; m < 4; ++m) aq[m] = LDA(P, 0, m); \
    _Pragma("unroll") \
    for (int n = 0; n < 4; ++n) bq[n] = LDB(P, 0, n); \
    if (STG) stage_chunk(Ag, ld, lds, ((P^1)*2 + 0) * 16384, (KTN), tid, wave); \
    __builtin_amdgcn_s_setprio(1); QMFMA(0); __builtin_amdgcn_s_setprio(0); \
    SBAR(); \
    /* ---- ph2: mh1, ks0 ---- */ \
    _Pragma("unroll") \
    for (int m = 0; m < 4; ++m) aq[m] = LDA(P, 0, 4 + m); \
    if (STG) { stage_chunk(Bg, ld, lds, 65536 + ((P^1)*2 + 0) * 16384, (KTN), tid, wave); \
               VMCNT4(); } else { VMCNT0(); } \
    __builtin_amdgcn_s_setprio(1); QMFMA(4); __builtin_amdgcn_s_setprio(0); \
    SBAR(); \
    /* ---- ph3: mh0, ks1 ---- */ \
    _Pragma("unroll") \
    for (int m = 0; m < 4; ++m) aq[m] = LDA(P, 1, m); \
    _Pragma("unroll") \
    for (int n = 0; n < 4; ++n) bq[n] = LDB(P, 1, n); \
    if (STG) stage_chunk(Ag, ld, lds, ((P^1)*2 + 1) * 16384, (KTN) + 32, tid, wave); \
    __builtin_amdgcn_s_setprio(1); QMFMA(0); __builtin_amdgcn_s_setprio(0); \
    SBAR(); \
    /* ---- ph4: mh1, ks1 ---- */ \
    _Pragma("unroll") \
    for (int m = 0; m < 4; ++m) aq[m] = LDA(P, 1, 4 + m); \
    if (STG) { stage_chunk(Bg, ld, lds, 65536 + ((P^1)*2 + 1) * 16384, (KTN) + 32, tid, wave); \
               VMCNT4(); } \
    __builtin_amdgcn_s_setprio(1); QMFMA(4); __builtin_amdgcn_s_setprio(0); \
    SBAR(); \
} while (0)

    // prologue: stage tile 0 (order A0, B0, A1, B1), wait oldest 4
    stage_chunk(Ag, ld, lds, 0 * 16384, 0, tid, wave);
    stage_chunk(Bg, ld, lds, 65536 + 0 * 16384, 0, tid, wave);
    stage_chunk(Ag, ld, lds, 1 * 16384, 32, tid, wave);
    stage_chunk(Bg, ld, lds, 65536 + 1 * 16384, 32, tid, wave);
    VMCNT4();
    SBAR();

    // nt K-tiles (nt even): (nt-2)/2 pairs + penultimate + peeled tail
#pragma unroll 1
    for (int tp = 0; tp < (nt - 2) / 2; ++tp) {
        TILE(0, (2 * tp + 1) * 64, 1);
        TILE(1, (2 * tp + 2) * 64, 1);
    }
    TILE(0, (nt - 1) * 64, 1);
    TILE(1, 0, 0);

#undef TILE
#undef QMFMA
#undef LDB
#undef LDA

    // epilogue: f32 partial slab write
    const size_t zo = (size_t)blockIdx.z * ((size_t)BATCH * NODES);
    const int grow0 = blockIdx.x * 256 + wr * 128 + (lhi << 2);
    const int gcol0 = blockIdx.y * 256 + wcn * 64 + l15;
#pragma unroll
    for (int m = 0; m < 8; ++m)
#pragma unroll
        for (int n = 0; n < 4; ++n)
#pragma unroll
            for (int j = 0; j < 4; ++j)
                outf[zo + (size_t)(grow0 + m * 16 + j) * NODES + gcol0 + n * 16] =
                    acc[m][n][j];
}

// ---------------------------------------------------------------------------
// C = A[M,K] @ B[N,K]^T (bf16). 128x128 tile, BK=64, 2-phase dbuf, T2 swizzle.
// EP: 2 d = (acc + b1[col] > 0) ? bf16(w2sum[col]) : 0
//     3 s2 = bf16(stateb[row,col] - 0.1*sign(acc))   (aux0 = bf16 state)
// ---------------------------------------------------------------------------
template<int EP>
__global__ __launch_bounds__(256) void gemm_bt(
    const u16* __restrict__ A, const u16* __restrict__ B, int K, int N,
    const float* __restrict__ aux0, const float* __restrict__ aux1,
    u16* __restrict__ outb)
{
    __shared__ u16 As[2][128 * 64];
    __shared__ u16 Bs[2][128 * 64];
    const int tid = threadIdx.x;
    const int wave = tid >> 6, lane = tid & 63;
    const int wr = wave >> 1, wc = wave & 1;
    const int l15 = lane & 15, lhi = lane >> 4;
    const int swz = (l15 & 7) << 3;
    const int src_c = (((lane & 7) ^ (lane >> 3)) << 3);
    const int src_r = lane >> 3;
    const u16* Ag = A + (size_t)(blockIdx.x * 128) * K;
    const u16* Bg = B + (size_t)(blockIdx.y * 128) * K;

    v4f acc[4][4];
#pragma unroll
    for (int m = 0; m < 4; ++m)
#pragma unroll
        for (int n = 0; n < 4; ++n) acc[m][n] = (v4f){0.f, 0.f, 0.f, 0.f};

#pragma unroll
    for (int i = 0; i < 4; ++i) {
        int chunk = wave * 4 + i;
        int r = chunk * 8 + src_r;
        gload16(Ag + (size_t)r * K + src_c, &As[0][chunk * 512]);
        gload16(Bg + (size_t)r * K + src_c, &Bs[0][chunk * 512]);
    }
    __syncthreads();

    int cur = 0;
    for (int kt = 0; kt < K; kt += 64) {
        if (kt + 64 < K) {
            int nxt = cur ^ 1;
#pragma unroll
            for (int i = 0; i < 4; ++i) {
                int chunk = wave * 4 + i;
                int r = chunk * 8 + src_r;
                gload16(Ag + (size_t)r * K + (kt + 64 + src_c), &As[nxt][chunk * 512]);
                gload16(Bg + (size_t)r * K + (kt + 64 + src_c), &Bs[nxt][chunk * 512]);
            }
        }
#pragma unroll
        for (int ks = 0; ks < 2; ++ks) {
            v8s a[4], b[4];
#pragma unroll
            for (int m = 0; m < 4; ++m)
                a[m] = *reinterpret_cast<const v8s*>(
                    &As[cur][(wr * 64 + m * 16 + l15) * 64 + ((ks * 32 + (lhi << 3)) ^ swz)]);
#pragma unroll
            for (int n = 0; n < 4; ++n)
                b[n] = *reinterpret_cast<const v8s*>(
                    &Bs[cur][(wc * 64 + n * 16 + l15) * 64 + ((ks * 32 + (lhi << 3)) ^ swz)]);
#pragma unroll
            for (int m = 0; m < 4; ++m)
#pragma unroll
                for (int n = 0; n < 4; ++n)
                    acc[m][n] = __builtin_amdgcn_mfma_f32_16x16x32_bf16(
                        a[m], b[n], acc[m][n], 0, 0, 0);
        }
        __syncthreads();
        cur ^= 1;
    }

    const int m0 = blockIdx.x * 128 + wr * 64;
    const int n0 = blockIdx.y * 128 + wc * 64;
#pragma unroll
    for (int m = 0; m < 4; ++m) {
#pragma unroll
        for (int j = 0; j < 4; ++j) {
            int row = m0 + m * 16 + (lhi << 2) + j;
#pragma unroll
            for (int n = 0; n < 4; ++n) {
                int col = n0 + n * 16 + l15;
                float v = acc[m][n][j];
                size_t off = (size_t)row * N + col;
                if (EP == 2) {
                    float h = v + aux0[col];
                    outb[off] = (h > 0.f) ? f2b(aux1[col]) : (u16)0;
                } else {
                    float sg = (v > 0.f) ? 1.f : ((v < 0.f) ? -1.f : 0.f);
                    float sv = b2f(((const u16*)aux0)[off]);
                    outb[off] = f2b(sv - 0.1f * sg);
                }
            }
        }
    }
}

// ---------------------------------------------------------------------------
// Fused final policy: h2 = relu(s2 @ W1^T + b1), logits = h2 @ W2^T + b2,
// softmax(64) -> probs. T2 swizzle throughout.
// ---------------------------------------------------------------------------
__global__ __launch_bounds__(256) void policy_final(
    const u16* __restrict__ S2, const u16* __restrict__ W1b,
    const float* __restrict__ b1, const u16* __restrict__ W2b,
    const float* __restrict__ b2, float* __restrict__ probs)
{
    __shared__ u16 As[128 * 64];
    __shared__ u16 Bs[128 * 64];
    __shared__ u16 H2[128 * 128];
    const int tid = threadIdx.x;
    const int wave = tid >> 6, lane = tid & 63;
    const int wr = wave >> 1, wc = wave & 1;
    const int l15 = lane & 15, lhi = lane >> 4;
    const int swz = (l15 & 7) << 3;
    const int src_c = (((lane & 7) ^ (lane >> 3)) << 3);
    const int src_r = lane >> 3;
    const u16* Ag = S2 + (size_t)(blockIdx.x * 128) * NODES;

    v4f acc[4][4];
#pragma unroll
    for (int m = 0; m < 4; ++m)
#pragma unroll
        for (int n = 0; n < 4; ++n) acc[m][n] = (v4f){0.f, 0.f, 0.f, 0.f};

    for (int kt = 0; kt < NODES; kt += 64) {
#pragma unroll
        for (int i = 0; i < 4; ++i) {
            int chunk = wave * 4 + i;
            int r = chunk * 8 + src_r;
            gload16(Ag + (size_t)r * NODES + (kt + src_c), &As[chunk * 512]);
            gload16(W1b + (size_t)r * NODES + (kt + src_c), &Bs[chunk * 512]);
        }
        __syncthreads();
#pragma unroll
        for (int ks = 0; ks < 2; ++ks) {
            v8s a[4], b[4];
#pragma unroll
            for (int m = 0; m < 4; ++m)
                a[m] = *reinterpret_cast<const v8s*>(
                    &As[(wr * 64 + m * 16 + l15) * 64 + ((ks * 32 + (lhi << 3)) ^ swz)]);
#pragma unroll
            for (int n = 0; n < 4; ++n)
                b[n] = *reinterpret_cast<const v8s*>(
                    &Bs[(wc * 64 + n * 16 + l15) * 64 + ((ks * 32 + (lhi << 3)) ^ swz)]);
#pragma unroll
            for (int m = 0; m < 4; ++m)
#pragma unroll
                for (int n = 0; n < 4; ++n)
                    acc[m][n] = __builtin_amdgcn_mfma_f32_16x16x32_bf16(
                        a[m], b[n], acc[m][n], 0, 0, 0);
        }
        __syncthreads();
    }

#pragma unroll
    for (int m = 0; m < 4; ++m)
#pragma unroll
        for (int j = 0; j < 4; ++j) {
            int lrow = wr * 64 + m * 16 + (lhi << 2) + j;
#pragma unroll
            for (int n = 0; n < 4; ++n) {
                int col = wc * 64 + n * 16 + l15;
                float v = acc[m][n][j] + b1[col];
                H2[lrow * 128 + (col ^ ((lrow & 7) << 3))] = f2b(v > 0.f ? v : 0.f);
            }
        }
#pragma unroll
    for (int i = 0; i < 4; ++i) {
        int e = (tid + i * 256) * 8;
        int row = e >> 7, col = e & 127;
        int dst = (row << 7) | (col ^ ((row & 7) << 3));
        *reinterpret_cast<v8s*>(&Bs[dst]) = *reinterpret_cast<const v8s*>(&W2b[e]);
    }
    __syncthreads();

    v4f a2[2][4];
#pragma unroll
    for (int m = 0; m < 2; ++m)
#pragma unroll
        for (int n = 0; n < 4; ++n) a2[m][n] = (v4f){0.f, 0.f, 0.f, 0.f};
#pragma unroll
    for (int ks = 0; ks < 4; ++ks) {
        v8s af[2], bf[4];
#pragma unroll
        for (int m = 0; m < 2; ++m)
            af[m] = *reinterpret_cast<const v8s*>(
                &H2[(wave * 32 + m * 16 + l15) * 128 + ((ks * 32 + (lhi << 3)) ^ swz)]);
#pragma unroll
        for (int n = 0; n < 4; ++n)
            bf[n] = *reinterpret_cast<const v8s*>(
                &Bs[(n * 16 + l15) * 128 + ((ks * 32 + (lhi << 3)) ^ swz)]);
#pragma unroll
        for (int m = 0; m < 2; ++m)
#pragma unroll
            for (int n = 0; n < 4; ++n)
                a2[m][n] = __builtin_amdgcn_mfma_f32_16x16x32_bf16(
                    af[m], bf[n], a2[m][n], 0, 0, 0);
    }

#pragma unroll
    for (int m = 0; m < 2; ++m) {
#pragma unroll
        for (int j = 0; j < 4; ++j) {
            int lrow = wave * 32 + m * 16 + (lhi << 2) + j;
            float v[4];
#pragma unroll
            for (int n = 0; n < 4; ++n) v[n] = a2[m][n][j] + b2[n * 16 + l15];
            float mx = fmaxf(fmaxf(v[0], v[1]), fmaxf(v[2], v[3]));
#pragma unroll
            for (int s = 8; s >= 1; s >>= 1) mx = fmaxf(mx, __shfl_xor(mx, s));
            float e[4], sum = 0.f;
#pragma unroll
            for (int n = 0; n < 4; ++n) { e[n] = expf(v[n] - mx); sum += e[n]; }
#pragma unroll
            for (int s = 8; s >= 1; s >>= 1) sum += __shfl_xor(sum, s);
            float inv = 1.0f / sum;
            size_t base = (size_t)(blockIdx.x * 128 + lrow) * ACTIONS;
#pragma unroll
            for (int n = 0; n < 4; ++n) probs[base + n * 16 + l15] = e[n] * inv;
        }
    }
}

// ---------------------------------------------------------------------------
extern "C" void kernel_launch(void* const* d_in, const int* in_sizes, int n_in,
                              void* d_out, int out_size, void* d_ws, size_t ws_size,
                              hipStream_t stream)
{
    const float* E   = (const float*)d_in[0];
    const float* S   = (const float*)d_in[1];
    const float* Adj = (const float*)d_in[2];
    const float* Msk = (const float*)d_in[3];
    const float* W1  = (const float*)d_in[4];
    const float* b1  = (const float*)d_in[5];
    const float* W2  = (const float*)d_in[6];
    const float* b2  = (const float*)d_in[7];
    float* out = (float*)d_out;

    char* ws = (char*)d_ws;
    u16*  Ebf  = (u16*)  (ws + 0UL);          // 167772160 (dead after gemm8 #1)
    u16*  Sbf  = (u16*)  (ws + 167772160UL);  // 20971520
    u16*  Atb  = (u16*)  (ws + 188743680UL);  // 2097152
    u16*  W1b  = (u16*)  (ws + 190840832UL);  // 262144
    u16*  W1tb = (u16*)  (ws + 191102976UL);  // 262144
    u16*  W2b  = (u16*)  (ws + 191365120UL);  // 16384
    float* w2s = (float*)(ws + 191381504UL);  // 512
    float* keep= (float*)(ws + 191382016UL);  // 32768
    float* part= (float*)(ws + 191414784UL);  // 1024
    u16*  filt = (u16*)  (ws + 191415808UL);  // 16777216
    // GEMM1 split-K f32 partials (2 x 33554432 B); dead after combine,
    // region then reused for stb/dbuf/s2 (temporally disjoint).
    float* pbuf = (float*)(ws + 208193024UL); // 67108864
    u16*  stb  = (u16*)  (ws + 208193024UL);  // 16777216
    u16*  dbuf = (u16*)  (ws + 224970240UL);  // 2097152
    u16*  s2   = (u16*)  (ws + 227067392UL);  // 16777216
    // GEMM2 split-K f32 partials reuse the dead Ebf region (64 MB).
    float* p2  = (float*)(ws + 0UL);

    hipFuncSetAttribute((const void*)gemm8_ep0,
                        hipFuncAttributeMaxDynamicSharedMemorySize, 131072);

    dim3 tb(32, 8);
    hist_entropy_cast<<<8192, 256, 0, stream>>>(E, Ebf, keep);
    cvt_bf16<<<2048, 256, 0, stream>>>(S, Sbf, (long)NODES * IND / 4);
    cvt_bf16<<<128, 256, 0, stream>>>(W1, W1b, (long)HIDDEN * NODES / 4);
    cvt_bf16<<<8, 256, 0, stream>>>(W2, W2b, (long)ACTIONS * HIDDEN / 4);
    transpose_cvt<<<dim3(32, 32), tb, 0, stream>>>(Adj, Atb, NODES, NODES);
    transpose_cvt<<<dim3(32, 4),  tb, 0, stream>>>(W1, W1tb, HIDDEN, NODES);
    w2sum_k<<<1, 128, 0, stream>>>(W2, w2s);
    semloss1<<<256, 256, 0, stream>>>(Adj, Msk, part);
    semloss2<<<1, 256, 0, stream>>>(part, out + 524288 + 1048576, 256);
    hipMemcpyAsync(out + 524288, Adj, sizeof(float) * 1048576,
                   hipMemcpyDeviceToDevice, stream);

    // compressed = E @ S^T  (256^2 single-barrier counted-vmcnt, split-K x2)
    gemm8_ep0<<<dim3(32, 4, 2), 512, 131072, stream>>>(Ebf, Sbf, IND, 80, pbuf);
    // filtered = bf16((p0+p1) * keep)
    combine_k<1><<<8192, 256, 0, stream>>>(pbuf, pbuf + (size_t)BATCH * NODES,
                                           keep, filt);
    // state = filtered @ adjacency: same kernel, ld=1024, nt=8, split-K x2
    // (partials in dead Ebf region)
    gemm8_ep0<<<dim3(32, 4, 2), 512, 131072, stream>>>(filt, Atb, NODES, 8, p2);
    combine_k<0><<<8192, 256, 0, stream>>>(p2, p2 + (size_t)BATCH * NODES,
                                           nullptr, stb);
    // d = relu'(state@W1^T+b1) * w2sum  (bf16)
    gemm_bt<2><<<dim3(64, 1), 256, 0, stream>>>(stb, W1b, NODES, HIDDEN,
                                                b1, w2s, dbuf);
    // s2 = state - 0.1*sign(d @ W1)  (bf16)
    gemm_bt<3><<<dim3(64, 8), 256, 0, stream>>>(dbuf, W1tb, HIDDEN, NODES,
                                                (const float*)stb, nullptr, s2);
    // probs = softmax(relu(s2@W1^T+b1)@W2^T + b2)
    policy_final<<<64, 256, 0, stream>>>(s2, W1b, b1, W2b, b2, out);
}

// Round 13
// 383.476 us; speedup vs baseline: 1.0467x; 1.0467x over previous
//
#include <hip/hip_runtime.h>
#include <hip/hip_bf16.h>

typedef unsigned short u16;
typedef short v8s __attribute__((ext_vector_type(8)));
typedef float v4f __attribute__((ext_vector_type(4)));

#define BATCH 8192
#define IND 10240
#define NODES 1024
#define ACTIONS 64
#define HIDDEN 128

__device__ __forceinline__ u16 f2b(float x) {
    __hip_bfloat16 h = __float2bfloat16(x);
    return *reinterpret_cast<u16*>(&h);
}

__device__ __forceinline__ float b2f(u16 x) {
    unsigned u = ((unsigned)x) << 16;
    return *reinterpret_cast<float*>(&u);
}

__device__ __forceinline__ void gload16(const void* g, void* l) {
    __builtin_amdgcn_global_load_lds(
        (const __attribute__((address_space(1))) void*)g,
        (__attribute__((address_space(3))) void*)l, 16, 0, 0);
}

#define SBAR() do { __builtin_amdgcn_s_barrier(); \
                    __builtin_amdgcn_sched_barrier(0); } while (0)
#define VMCNT6() asm volatile("s_waitcnt vmcnt(6)" ::: "memory")
#define VMCNT4() asm volatile("s_waitcnt vmcnt(4)" ::: "memory")
#define VMCNT0() asm volatile("s_waitcnt vmcnt(0)" ::: "memory")

// ---------------------------------------------------------------------------
// Histogram + entropy gate + E -> bf16 cast (one pass over E).
// ---------------------------------------------------------------------------
__global__ __launch_bounds__(256) void hist_entropy_cast(
    const float* __restrict__ E, u16* __restrict__ Ebf, float* __restrict__ keep)
{
    __shared__ int hist[4][100];
    const int tid = threadIdx.x;
    const int wave = tid >> 6;
    const int b = blockIdx.x;
    for (int j = tid; j < 400; j += 256) ((int*)hist)[j] = 0;
    __syncthreads();

    const float* row = E + (size_t)b * IND;
    u16* orow = Ebf + (size_t)b * IND;
    for (int i = tid * 4; i < IND; i += 1024) {
        float4 v = *reinterpret_cast<const float4*>(row + i);
        float xs[4] = {v.x, v.y, v.z, v.w};
        u16 ob[4];
#pragma unroll
        for (int j = 0; j < 4; ++j) {
            float x = xs[j];
            ob[j] = f2b(x);
            if (x >= -5.0f && x <= 5.0f) {
                int idx = (int)floorf((x + 5.0f) / 10.0f * 100.0f);
                idx = idx < 0 ? 0 : (idx > 99 ? 99 : idx);
                atomicAdd(&hist[wave][idx], 1);
            }
        }
        u16 packed[4] = {ob[0], ob[1], ob[2], ob[3]};
        *reinterpret_cast<uint2*>(orow + i) = *reinterpret_cast<uint2*>(packed);
    }
    __syncthreads();
    if (tid < 100)
        hist[0][tid] = hist[0][tid] + hist[1][tid] + hist[2][tid] + hist[3][tid];
    __syncthreads();

    if (tid < 64) {
        float c0 = (float)hist[0][tid];
        float c1 = (tid < 36) ? (float)hist[0][tid + 64] : 0.0f;
        float tot = c0 + c1;
#pragma unroll
        for (int s = 32; s >= 1; s >>= 1) tot += __shfl_xor(tot, s);
        float denom = tot + 1e-9f;
        float p0 = c0 / denom, p1 = c1 / denom;
        float e = -(p0 * logf(p0 + 1e-9f)) - (p1 * logf(p1 + 1e-9f));
#pragma unroll
        for (int s = 32; s >= 1; s >>= 1) e += __shfl_xor(e, s);
        if (tid == 0) keep[b] = (e >= 2.5f) ? 1.0f : 0.0f;
    }
}

// ---------------------------------------------------------------------------
// f32 -> bf16 elementwise
// ---------------------------------------------------------------------------
__global__ __launch_bounds__(256) void cvt_bf16(
    const float* __restrict__ in, u16* __restrict__ out, long n4)
{
    long i = (long)blockIdx.x * blockDim.x + threadIdx.x;
    const long stride = (long)gridDim.x * blockDim.x;
    for (; i < n4; i += stride) {
        float4 v = reinterpret_cast<const float4*>(in)[i];
        u16 o[4] = {f2b(v.x), f2b(v.y), f2b(v.z), f2b(v.w)};
        reinterpret_cast<uint2*>(out)[i] = *reinterpret_cast<uint2*>(o);
    }
}

// ---------------------------------------------------------------------------
// transpose + convert: in f32 [R][C] -> out bf16 [C][R]
// ---------------------------------------------------------------------------
__global__ void transpose_cvt(const float* __restrict__ in, u16* __restrict__ out,
                              int R, int C)
{
    __shared__ float t[32][33];
    const int bx = blockIdx.x * 32, by = blockIdx.y * 32;
    const int tx = threadIdx.x, ty = threadIdx.y;  // 32 x 8
#pragma unroll
    for (int j = 0; j < 32; j += 8) {
        int r = by + ty + j, c = bx + tx;
        if (r < R && c < C) t[ty + j][tx] = in[(size_t)r * C + c];
    }
    __syncthreads();
#pragma unroll
    for (int j = 0; j < 32; j += 8) {
        int oc = by + tx;
        int orow = bx + ty + j;
        if (orow < C && oc < R) out[(size_t)orow * R + oc] = f2b(t[tx][ty + j]);
    }
}

// ---------------------------------------------------------------------------
// w2sum[i] = sum_a W2[a][i]
// ---------------------------------------------------------------------------
__global__ void w2sum_k(const float* __restrict__ W2, float* __restrict__ w2s)
{
    int i = threadIdx.x;
    if (i < HIDDEN) {
        float s = 0.f;
        for (int a = 0; a < ACTIONS; ++a) s += W2[a * HIDDEN + i];
        w2s[i] = s;
    }
}

// ---------------------------------------------------------------------------
// semantic loss reduction (2-stage, deterministic)
// ---------------------------------------------------------------------------
__global__ __launch_bounds__(256) void semloss1(
    const float* __restrict__ A, const float* __restrict__ M, float* __restrict__ part)
{
    const int tid = threadIdx.x;
    float s = 0.f;
    for (int i = blockIdx.x * 256 + tid; i < NODES * NODES; i += 256 * gridDim.x)
        s += fabsf(A[i]) * M[i];
    __shared__ float ws[4];
#pragma unroll
    for (int off = 32; off >= 1; off >>= 1) s += __shfl_xor(s, off);
    if ((tid & 63) == 0) ws[tid >> 6] = s;
    __syncthreads();
    if (tid == 0) part[blockIdx.x] = ws[0] + ws[1] + ws[2] + ws[3];
}

__global__ void semloss2(const float* __restrict__ part, float* __restrict__ out, int n)
{
    const int tid = threadIdx.x;
    float s = (tid < n) ? part[tid] : 0.f;
    __shared__ float ws[4];
#pragma unroll
    for (int off = 32; off >= 1; off >>= 1) s += __shfl_xor(s, off);
    if ((tid & 63) == 0) ws[tid >> 6] = s;
    __syncthreads();
    if (tid == 0) out[0] = ws[0] + ws[1] + ws[2] + ws[3];
}

// ---------------------------------------------------------------------------
// combine split-K partials: filt = bf16((p0+p1) * keep[row])
// ---------------------------------------------------------------------------
__global__ __launch_bounds__(256) void combine_keep(
    const float* __restrict__ p0, const float* __restrict__ p1,
    const float* __restrict__ keep, u16* __restrict__ filt)
{
    long base = ((long)blockIdx.x * 256 + threadIdx.x) * 4;
    float4 a = *reinterpret_cast<const float4*>(p0 + base);
    float4 b = *reinterpret_cast<const float4*>(p1 + base);
    float k = keep[base >> 10];
    u16 o[4] = {f2b((a.x + b.x) * k), f2b((a.y + b.y) * k),
                f2b((a.z + b.z) * k), f2b((a.w + b.w) * k)};
    *reinterpret_cast<uint2*>(filt + base) = *reinterpret_cast<uint2*>(o);
}

// ---------------------------------------------------------------------------
// 256x256x(K=5120 per z) bf16 GEMM, C = A @ B^T, f32 partials (split-K x2).
// 8 waves (2M x 4N), wave tile 128x64 (MFMA:ds_read = 2.67, best measured
// shape). LDS (128 KiB dyn): A chunk (buf,kh) at (buf*2+kh)*16384, B at
// 65536+...; chunk [256 rows][4 x 16B blocks], block XOR-swizzled by
// (row>>1)&3; stage side linear dest + inverse-swizzled global source.
//
// Per K-tile t, 4 phases ph(ks,nh): {ds_read frags; stage one chunk of t+1
// (order Ak0,Bk0,Ak1,Bk1); [counted vmcnt]; s_barrier; setprio(1); 16 MFMA;
// setprio(0); s_barrier}.
// LAZY counted waits (in-order vmcnt retirement):
//   ph2: vmcnt(6) forces A1(t)   (read by ph3; issued t-1.ph3, aged 3 ph)
//   ph3: vmcnt(6) forces B1(t)   (read by ph4; issued t-1.ph4, aged 3 ph)
//   ph4: vmcnt(4) forces A0,B0(t+1) (read by t+1.ph1/ph2)
// Never drained to 0 inside the loop; peeled last tile drains once.
// ---------------------------------------------------------------------------
__device__ __forceinline__ void stage_chunk(
    const u16* __restrict__ g, char* lds, int chunk_off, int kt_col,
    int tid, int wave)
{
    const int s_row0 = tid >> 2;
    const int gblk = (tid & 3) ^ ((tid >> 3) & 3);  // inverse swizzle
#pragma unroll
    for (int j = 0; j < 2; ++j) {
        int lrow = j * 128 + s_row0;
        gload16(g + (size_t)lrow * IND + kt_col + (gblk << 3),
                lds + chunk_off + j * 8192 + (wave << 10));
    }
}

__global__ __launch_bounds__(512, 2) void gemm8_ep0(
    const u16* __restrict__ A, const u16* __restrict__ B,
    float* __restrict__ outf)
{
    extern __shared__ char lds[];
    const int tid = threadIdx.x;
    const int wave = tid >> 6, lane = tid & 63;
    const int wr = wave >> 2, wcn = wave & 3;   // 2M x 4N
    const int l15 = lane & 15, lhi = lane >> 4;
    const int rsw = (lhi ^ ((l15 >> 1) & 3)) << 4;  // read-side swizzled block byte
    const size_t koff = (size_t)blockIdx.z * (IND / 2);
    const u16* Ag = A + (size_t)(blockIdx.x * 256) * IND + koff;
    const u16* Bg = B + (size_t)(blockIdx.y * 256) * IND + koff;

    v4f acc[8][4];
#pragma unroll
    for (int m = 0; m < 8; ++m)
#pragma unroll
        for (int n = 0; n < 4; ++n) acc[m][n] = (v4f){0.f, 0.f, 0.f, 0.f};

    v8s a[8], b0, b1;
    const int arow = wr * 128 * 64;        // byte offset of wave's A row range
    const int brow0 = wcn * 64 * 64;       // byte offset of wave's B row range

#define LDA(P, KS, M) (*reinterpret_cast<const v8s*>( \
    lds + ((P)*2 + (KS)) * 16384 + arow + ((M)*16 + l15) * 64 + rsw))
#define LDB(P, KS, NF) (*reinterpret_cast<const v8s*>( \
    lds + 65536 + ((P)*2 + (KS)) * 16384 + brow0 + ((NF)*16 + l15) * 64 + rsw))
#define MFMA2(NH) do { \
    _Pragma("unroll") \
    for (int m = 0; m < 8; ++m) { \
        acc[m][2*(NH)]   = __builtin_amdgcn_mfma_f32_16x16x32_bf16( \
            a[m], b0, acc[m][2*(NH)], 0, 0, 0); \
        acc[m][2*(NH)+1] = __builtin_amdgcn_mfma_f32_16x16x32_bf16( \
            a[m], b1, acc[m][2*(NH)+1], 0, 0, 0); \
    } } while (0)

#define TILE(P, KTN, STG) do { \
    /* ---- phase 1: ks=0, nh=0 ---- */ \
    _Pragma("unroll") \
    for (int m = 0; m < 8; ++m) a[m] = LDA(P, 0, m); \
    b0 = LDB(P, 0, 0); b1 = LDB(P, 0, 1); \
    if (STG) stage_chunk(Ag, lds, ((P^1)*2 + 0) * 16384, (KTN), tid, wave); \
    SBAR(); \
    __builtin_amdgcn_s_setprio(1); MFMA2(0); __builtin_amdgcn_s_setprio(0); \
    SBAR(); \
    /* ---- phase 2: ks=0, nh=1 ---- */ \
    b0 = LDB(P, 0, 2); b1 = LDB(P, 0, 3); \
    if (STG) { stage_chunk(Bg, lds, 65536 + ((P^1)*2 + 0) * 16384, (KTN), tid, wave); \
               VMCNT6(); } else { VMCNT0(); } \
    SBAR(); \
    __builtin_amdgcn_s_setprio(1); MFMA2(1); __builtin_amdgcn_s_setprio(0); \
    SBAR(); \
    /* ---- phase 3: ks=1, nh=0 ---- */ \
    _Pragma("unroll") \
    for (int m = 0; m < 8; ++m) a[m] = LDA(P, 1, m); \
    b0 = LDB(P, 1, 0); b1 = LDB(P, 1, 1); \
    if (STG) { stage_chunk(Ag, lds, ((P^1)*2 + 1) * 16384, (KTN) + 32, tid, wave); \
               VMCNT6(); } \
    SBAR(); \
    __builtin_amdgcn_s_setprio(1); MFMA2(0); __builtin_amdgcn_s_setprio(0); \
    SBAR(); \
    /* ---- phase 4: ks=1, nh=1 ---- */ \
    b0 = LDB(P, 1, 2); b1 = LDB(P, 1, 3); \
    if (STG) { stage_chunk(Bg, lds, 65536 + ((P^1)*2 + 1) * 16384, (KTN) + 32, tid, wave); \
               VMCNT4(); } \
    SBAR(); \
    __builtin_amdgcn_s_setprio(1); MFMA2(1); __builtin_amdgcn_s_setprio(0); \
    SBAR(); \
} while (0)

    // prologue: stage tile 0 (order Ak0, Bk0, Ak1, Bk1), wait oldest 4
    stage_chunk(Ag, lds, 0 * 16384, 0, tid, wave);
    stage_chunk(Bg, lds, 65536 + 0 * 16384, 0, tid, wave);
    stage_chunk(Ag, lds, 1 * 16384, 32, tid, wave);
    stage_chunk(Bg, lds, 65536 + 1 * 16384, 32, tid, wave);
    VMCNT4();
    SBAR();

    // 80 K-tiles: 39 pairs (t=0..77) + t=78 + peeled epilogue t=79
#pragma unroll 1
    for (int tp = 0; tp < 39; ++tp) {
        TILE(0, (2 * tp + 1) * 64, 1);
        TILE(1, (2 * tp + 2) * 64, 1);
    }
    TILE(0, 79 * 64, 1);
    TILE(1, 0, 0);

#undef TILE
#undef MFMA2
#undef LDB
#undef LDA

    // epilogue: f32 partial slab write
    const size_t zo = (size_t)blockIdx.z * ((size_t)BATCH * NODES);
    const int grow0 = blockIdx.x * 256 + wr * 128 + (lhi << 2);
    const int gcol0 = blockIdx.y * 256 + wcn * 64 + l15;
#pragma unroll
    for (int m = 0; m < 8; ++m)
#pragma unroll
        for (int n = 0; n < 4; ++n)
#pragma unroll
            for (int j = 0; j < 4; ++j)
                outf[zo + (size_t)(grow0 + m * 16 + j) * NODES + gcol0 + n * 16] =
                    acc[m][n][j];
}

// ---------------------------------------------------------------------------
// C = A[M,K] @ B[N,K]^T (bf16). 128x128 tile, BK=64, 2-phase dbuf, T2 swizzle.
// EP: 1 stateb = bf16(acc)
//     2 d = (acc + b1[col] > 0) ? bf16(w2sum[col]) : 0
//     3 s2 = bf16(stateb[row,col] - 0.1*sign(acc))   (aux0 = bf16 state)
// ---------------------------------------------------------------------------
template<int EP>
__global__ __launch_bounds__(256) void gemm_bt(
    const u16* __restrict__ A, const u16* __restrict__ B, int K, int N,
    const float* __restrict__ aux0, const float* __restrict__ aux1,
    u16* __restrict__ outb)
{
    __shared__ u16 As[2][128 * 64];
    __shared__ u16 Bs[2][128 * 64];
    const int tid = threadIdx.x;
    const int wave = tid >> 6, lane = tid & 63;
    const int wr = wave >> 1, wc = wave & 1;
    const int l15 = lane & 15, lhi = lane >> 4;
    const int swz = (l15 & 7) << 3;
    const int src_c = (((lane & 7) ^ (lane >> 3)) << 3);
    const int src_r = lane >> 3;
    const u16* Ag = A + (size_t)(blockIdx.x * 128) * K;
    const u16* Bg = B + (size_t)(blockIdx.y * 128) * K;

    v4f acc[4][4];
#pragma unroll
    for (int m = 0; m < 4; ++m)
#pragma unroll
        for (int n = 0; n < 4; ++n) acc[m][n] = (v4f){0.f, 0.f, 0.f, 0.f};

#pragma unroll
    for (int i = 0; i < 4; ++i) {
        int chunk = wave * 4 + i;
        int r = chunk * 8 + src_r;
        gload16(Ag + (size_t)r * K + src_c, &As[0][chunk * 512]);
        gload16(Bg + (size_t)r * K + src_c, &Bs[0][chunk * 512]);
    }
    __syncthreads();

    int cur = 0;
    for (int kt = 0; kt < K; kt += 64) {
        if (kt + 64 < K) {
            int nxt = cur ^ 1;
#pragma unroll
            for (int i = 0; i < 4; ++i) {
                int chunk = wave * 4 + i;
                int r = chunk * 8 + src_r;
                gload16(Ag + (size_t)r * K + (kt + 64 + src_c), &As[nxt][chunk * 512]);
                gload16(Bg + (size_t)r * K + (kt + 64 + src_c), &Bs[nxt][chunk * 512]);
            }
        }
#pragma unroll
        for (int ks = 0; ks < 2; ++ks) {
            v8s a[4], b[4];
#pragma unroll
            for (int m = 0; m < 4; ++m)
                a[m] = *reinterpret_cast<const v8s*>(
                    &As[cur][(wr * 64 + m * 16 + l15) * 64 + ((ks * 32 + (lhi << 3)) ^ swz)]);
#pragma unroll
            for (int n = 0; n < 4; ++n)
                b[n] = *reinterpret_cast<const v8s*>(
                    &Bs[cur][(wc * 64 + n * 16 + l15) * 64 + ((ks * 32 + (lhi << 3)) ^ swz)]);
#pragma unroll
            for (int m = 0; m < 4; ++m)
#pragma unroll
                for (int n = 0; n < 4; ++n)
                    acc[m][n] = __builtin_amdgcn_mfma_f32_16x16x32_bf16(
                        a[m], b[n], acc[m][n], 0, 0, 0);
        }
        __syncthreads();
        cur ^= 1;
    }

    const int m0 = blockIdx.x * 128 + wr * 64;
    const int n0 = blockIdx.y * 128 + wc * 64;
#pragma unroll
    for (int m = 0; m < 4; ++m) {
#pragma unroll
        for (int j = 0; j < 4; ++j) {
            int row = m0 + m * 16 + (lhi << 2) + j;
#pragma unroll
            for (int n = 0; n < 4; ++n) {
                int col = n0 + n * 16 + l15;
                float v = acc[m][n][j];
                size_t off = (size_t)row * N + col;
                if (EP == 1) {
                    outb[off] = f2b(v);
                } else if (EP == 2) {
                    float h = v + aux0[col];
                    outb[off] = (h > 0.f) ? f2b(aux1[col]) : (u16)0;
                } else {
                    float sg = (v > 0.f) ? 1.f : ((v < 0.f) ? -1.f : 0.f);
                    float sv = b2f(((const u16*)aux0)[off]);
                    outb[off] = f2b(sv - 0.1f * sg);
                }
            }
        }
    }
}

// ---------------------------------------------------------------------------
// Fused final policy: h2 = relu(s2 @ W1^T + b1), logits = h2 @ W2^T + b2,
// softmax(64) -> probs. T2 swizzle throughout.
// ---------------------------------------------------------------------------
__global__ __launch_bounds__(256) void policy_final(
    const u16* __restrict__ S2, const u16* __restrict__ W1b,
    const float* __restrict__ b1, const u16* __restrict__ W2b,
    const float* __restrict__ b2, float* __restrict__ probs)
{
    __shared__ u16 As[128 * 64];
    __shared__ u16 Bs[128 * 64];
    __shared__ u16 H2[128 * 128];
    const int tid = threadIdx.x;
    const int wave = tid >> 6, lane = tid & 63;
    const int wr = wave >> 1, wc = wave & 1;
    const int l15 = lane & 15, lhi = lane >> 4;
    const int swz = (l15 & 7) << 3;
    const int src_c = (((lane & 7) ^ (lane >> 3)) << 3);
    const int src_r = lane >> 3;
    const u16* Ag = S2 + (size_t)(blockIdx.x * 128) * NODES;

    v4f acc[4][4];
#pragma unroll
    for (int m = 0; m < 4; ++m)
#pragma unroll
        for (int n = 0; n < 4; ++n) acc[m][n] = (v4f){0.f, 0.f, 0.f, 0.f};

    for (int kt = 0; kt < NODES; kt += 64) {
#pragma unroll
        for (int i = 0; i < 4; ++i) {
            int chunk = wave * 4 + i;
            int r = chunk * 8 + src_r;
            gload16(Ag + (size_t)r * NODES + (kt + src_c), &As[chunk * 512]);
            gload16(W1b + (size_t)r * NODES + (kt + src_c), &Bs[chunk * 512]);
        }
        __syncthreads();
#pragma unroll
        for (int ks = 0; ks < 2; ++ks) {
            v8s a[4], b[4];
#pragma unroll
            for (int m = 0; m < 4; ++m)
                a[m] = *reinterpret_cast<const v8s*>(
                    &As[(wr * 64 + m * 16 + l15) * 64 + ((ks * 32 + (lhi << 3)) ^ swz)]);
#pragma unroll
            for (int n = 0; n < 4; ++n)
                b[n] = *reinterpret_cast<const v8s*>(
                    &Bs[(wc * 64 + n * 16 + l15) * 64 + ((ks * 32 + (lhi << 3)) ^ swz)]);
#pragma unroll
            for (int m = 0; m < 4; ++m)
#pragma unroll
                for (int n = 0; n < 4; ++n)
                    acc[m][n] = __builtin_amdgcn_mfma_f32_16x16x32_bf16(
                        a[m], b[n], acc[m][n], 0, 0, 0);
        }
        __syncthreads();
    }

#pragma unroll
    for (int m = 0; m < 4; ++m)
#pragma unroll
        for (int j = 0; j < 4; ++j) {
            int lrow = wr * 64 + m * 16 + (lhi << 2) + j;
#pragma unroll
            for (int n = 0; n < 4; ++n) {
                int col = wc * 64 + n * 16 + l15;
                float v = acc[m][n][j] + b1[col];
                H2[lrow * 128 + (col ^ ((lrow & 7) << 3))] = f2b(v > 0.f ? v : 0.f);
            }
        }
#pragma unroll
    for (int i = 0; i < 4; ++i) {
        int e = (tid + i * 256) * 8;
        int row = e >> 7, col = e & 127;
        int dst = (row << 7) | (col ^ ((row & 7) << 3));
        *reinterpret_cast<v8s*>(&Bs[dst]) = *reinterpret_cast<const v8s*>(&W2b[e]);
    }
    __syncthreads();

    v4f a2[2][4];
#pragma unroll
    for (int m = 0; m < 2; ++m)
#pragma unroll
        for (int n = 0; n < 4; ++n) a2[m][n] = (v4f){0.f, 0.f, 0.f, 0.f};
#pragma unroll
    for (int ks = 0; ks < 4; ++ks) {
        v8s af[2], bf[4];
#pragma unroll
        for (int m = 0; m < 2; ++m)
            af[m] = *reinterpret_cast<const v8s*>(
                &H2[(wave * 32 + m * 16 + l15) * 128 + ((ks * 32 + (lhi << 3)) ^ swz)]);
#pragma unroll
        for (int n = 0; n < 4; ++n)
            bf[n] = *reinterpret_cast<const v8s*>(
                &Bs[(n * 16 + l15) * 128 + ((ks * 32 + (lhi << 3)) ^ swz)]);
#pragma unroll
        for (int m = 0; m < 2; ++m)
#pragma unroll
            for (int n = 0; n < 4; ++n)
                a2[m][n] = __builtin_amdgcn_mfma_f32_16x16x32_bf16(
                    af[m], bf[n], a2[m][n], 0, 0, 0);
    }

#pragma unroll
    for (int m = 0; m < 2; ++m) {
#pragma unroll
        for (int j = 0; j < 4; ++j) {
            int lrow = wave * 32 + m * 16 + (lhi << 2) + j;
            float v[4];
#pragma unroll
            for (int n = 0; n < 4; ++n) v[n] = a2[m][n][j] + b2[n * 16 + l15];
            float mx = fmaxf(fmaxf(v[0], v[1]), fmaxf(v[2], v[3]));
#pragma unroll
            for (int s = 8; s >= 1; s >>= 1) mx = fmaxf(mx, __shfl_xor(mx, s));
            float e[4], sum = 0.f;
#pragma unroll
            for (int n = 0; n < 4; ++n) { e[n] = expf(v[n] - mx); sum += e[n]; }
#pragma unroll
            for (int s = 8; s >= 1; s >>= 1) sum += __shfl_xor(sum, s);
            float inv = 1.0f / sum;
            size_t base = (size_t)(blockIdx.x * 128 + lrow) * ACTIONS;
#pragma unroll
            for (int n = 0; n < 4; ++n) probs[base + n * 16 + l15] = e[n] * inv;
        }
    }
}

// ---------------------------------------------------------------------------
extern "C" void kernel_launch(void* const* d_in, const int* in_sizes, int n_in,
                              void* d_out, int out_size, void* d_ws, size_t ws_size,
                              hipStream_t stream)
{
    const float* E   = (const float*)d_in[0];
    const float* S   = (const float*)d_in[1];
    const float* Adj = (const float*)d_in[2];
    const float* Msk = (const float*)d_in[3];
    const float* W1  = (const float*)d_in[4];
    const float* b1  = (const float*)d_in[5];
    const float* W2  = (const float*)d_in[6];
    const float* b2  = (const float*)d_in[7];
    float* out = (float*)d_out;

    char* ws = (char*)d_ws;
    u16*  Ebf  = (u16*)  (ws + 0UL);          // 167772160
    u16*  Sbf  = (u16*)  (ws + 167772160UL);  // 20971520
    u16*  Atb  = (u16*)  (ws + 188743680UL);  // 2097152
    u16*  W1b  = (u16*)  (ws + 190840832UL);  // 262144
    u16*  W1tb = (u16*)  (ws + 191102976UL);  // 262144
    u16*  W2b  = (u16*)  (ws + 191365120UL);  // 16384
    float* w2s = (float*)(ws + 191381504UL);  // 512
    float* keep= (float*)(ws + 191382016UL);  // 32768
    float* part= (float*)(ws + 191414784UL);  // 1024
    u16*  filt = (u16*)  (ws + 191415808UL);  // 16777216
    // split-K f32 partial slabs (2 x 33554432 B); dead after combine_keep,
    // region then reused for stb/dbuf/s2 (temporally disjoint).
    float* pbuf = (float*)(ws + 208193024UL); // 67108864
    u16*  stb  = (u16*)  (ws + 208193024UL);  // 16777216
    u16*  dbuf = (u16*)  (ws + 224970240UL);  // 2097152
    u16*  s2   = (u16*)  (ws + 227067392UL);  // 16777216

    hipFuncSetAttribute((const void*)gemm8_ep0,
                        hipFuncAttributeMaxDynamicSharedMemorySize, 131072);

    dim3 tb(32, 8);
    hist_entropy_cast<<<8192, 256, 0, stream>>>(E, Ebf, keep);
    cvt_bf16<<<2048, 256, 0, stream>>>(S, Sbf, (long)NODES * IND / 4);
    cvt_bf16<<<128, 256, 0, stream>>>(W1, W1b, (long)HIDDEN * NODES / 4);
    cvt_bf16<<<8, 256, 0, stream>>>(W2, W2b, (long)ACTIONS * HIDDEN / 4);
    transpose_cvt<<<dim3(32, 32), tb, 0, stream>>>(Adj, Atb, NODES, NODES);
    transpose_cvt<<<dim3(32, 4),  tb, 0, stream>>>(W1, W1tb, HIDDEN, NODES);
    w2sum_k<<<1, 128, 0, stream>>>(W2, w2s);
    semloss1<<<256, 256, 0, stream>>>(Adj, Msk, part);
    semloss2<<<1, 256, 0, stream>>>(part, out + 524288 + 1048576, 256);
    hipMemcpyAsync(out + 524288, Adj, sizeof(float) * 1048576,
                   hipMemcpyDeviceToDevice, stream);

    // compressed = E @ S^T  (256^2 8-wave counted-vmcnt kernel, split-K x2)
    gemm8_ep0<<<dim3(32, 4, 2), 512, 131072, stream>>>(Ebf, Sbf, pbuf);
    // filtered = bf16((p0+p1) * keep)
    combine_keep<<<8192, 256, 0, stream>>>(pbuf, pbuf + (size_t)BATCH * NODES,
                                           keep, filt);
    // state = filtered @ adjacency  (bf16)
    gemm_bt<1><<<dim3(64, 8), 256, 0, stream>>>(filt, Atb, NODES, NODES,
                                                nullptr, nullptr, stb);
    // d = relu'(state@W1^T+b1) * w2sum  (bf16)
    gemm_bt<2><<<dim3(64, 1), 256, 0, stream>>>(stb, W1b, NODES, HIDDEN,
                                                b1, w2s, dbuf);
    // s2 = state - 0.1*sign(d @ W1)  (bf16)
    gemm_bt<3><<<dim3(64, 8), 256, 0, stream>>>(dbuf, W1tb, HIDDEN, NODES,
                                                (const float*)stb, nullptr, s2);
    // probs = softmax(relu(s2@W1^T+b1)@W2^T + b2)
    policy_final<<<64, 256, 0, stream>>>(s2, W1b, b1, W2b, b2, out);
}